// Round 10
// baseline (413.123 us; speedup 1.0000x reference)
//
#include <hip/hip_runtime.h>
#include <hip/hip_bf16.h>
#include <math.h>

#define DM   512
#define HH   8
#define RR   8
#define TT   128
#define BBATCH 32
#define MM   (TT*BBATCH)     // 4096 rows
#define NPROJ 2656
#define KQV  2560

typedef __attribute__((ext_vector_type(8))) short bf16x8;
typedef __attribute__((ext_vector_type(4))) float f32x4;

__device__ __forceinline__ float sigmoidf_(float x) {
    return 1.0f / (1.0f + __expf(-x));
}

__device__ __forceinline__ void gload_lds16(const void* g, void* l) {
    __builtin_amdgcn_global_load_lds(
        (const __attribute__((address_space(1))) unsigned int*)g,
        (__attribute__((address_space(3))) unsigned int*)l, 16, 0, 0);
}

// ---- DPP wave64 sum -> uniform value --------------------------------------
template<int CTRL, int RMASK>
__device__ __forceinline__ float dpp_add_(float x) {
    union { float f; int i; } a, b;
    a.f = x;
    b.i = __builtin_amdgcn_update_dpp(0, a.i, CTRL, RMASK, 0xf, true);
    return x + b.f;
}
__device__ __forceinline__ float wave_sum_u(float x) {
    x = dpp_add_<0x111, 0xf>(x);
    x = dpp_add_<0x112, 0xf>(x);
    x = dpp_add_<0x114, 0xf>(x);
    x = dpp_add_<0x118, 0xf>(x);
    x = dpp_add_<0x142, 0xa>(x);
    x = dpp_add_<0x143, 0xc>(x);
    union { float f; int i; } s, t;
    s.f = x;
    t.i = __builtin_amdgcn_readlane(s.i, 63);
    return t.f;
}

// ---------------- kernel 1: w_proj f32->bf16 + LN1 (critical path only) ----
__global__ __launch_bounds__(256) void f2b_wp_ln(
    const float* __restrict__ wp, __hip_bfloat16* __restrict__ wpb,
    const float* __restrict__ x, const float* __restrict__ g,
    const float* __restrict__ b, __hip_bfloat16* __restrict__ lnout)
{
    if (blockIdx.x < 1328) {          // 1328*256 = 339968 quads = 2656x512/4
        int q = blockIdx.x * 256 + threadIdx.x;
        int i4 = q * 4;
        float4 v = *(const float4*)(wp + i4);
        __hip_bfloat16* dst = wpb + i4;
        dst[0] = __float2bfloat16(v.x);
        dst[1] = __float2bfloat16(v.y);
        dst[2] = __float2bfloat16(v.z);
        dst[3] = __float2bfloat16(v.w);
        return;
    }
    int row = blockIdx.x - 1328;
    int tid = threadIdx.x;
    const float* xr = x + (size_t)row * DM;
    float2 v = ((const float2*)xr)[tid];
    float s = v.x + v.y;
    #pragma unroll
    for (int off = 32; off; off >>= 1) s += __shfl_down(s, off);
    __shared__ float red[8];
    int wid = tid >> 6, lane = tid & 63;
    if (lane == 0) red[wid] = s;
    __syncthreads();
    if (tid == 0) red[0] = (red[0] + red[1] + red[2] + red[3]) * (1.0f / DM);
    __syncthreads();
    float mean = red[0];
    float dx = v.x - mean, dy = v.y - mean;
    float sq = dx*dx + dy*dy;
    #pragma unroll
    for (int off = 32; off; off >>= 1) sq += __shfl_down(sq, off);
    if (lane == 0) red[4 + wid] = sq;
    __syncthreads();
    if (tid == 0) red[1] = rsqrtf((red[4]+red[5]+red[6]+red[7]) * (1.0f/DM) + 1e-5f);
    __syncthreads();
    float rstd = red[1];
    float2 gg = ((const float2*)g)[tid];
    float2 bb = ((const float2*)b)[tid];
    __hip_bfloat16* orow = lnout + (size_t)row * DM;
    orow[2*tid+0] = __float2bfloat16(dx * rstd * gg.x + bb.x);
    orow[2*tid+1] = __float2bfloat16(dy * rstd * gg.y + bb.y);
}

// ---------------- bf16 MFMA GEMM core: 128x128 tile, BK=32 ----------------
__device__ __forceinline__ void gemm_core128(
    const __hip_bfloat16* __restrict__ A, const __hip_bfloat16* __restrict__ W,
    const float* __restrict__ bias,
    float* __restrict__ Cf, __hip_bfloat16* __restrict__ Cb,
    int N, int K, int act, int m0, int n0,
    __hip_bfloat16* As, __hip_bfloat16* Bs)
{
    int tid = threadIdx.x;
    int wave = tid >> 6, lane = tid & 63;
    int wm = (wave >> 1) * 64, wn = (wave & 1) * 64;
    int fr = lane & 15, fq = lane >> 4;

    f32x4 acc[4][4];
    #pragma unroll
    for (int i = 0; i < 4; ++i)
        #pragma unroll
        for (int j = 0; j < 4; ++j)
            acc[i][j] = (f32x4){0.f, 0.f, 0.f, 0.f};

    int sm0 = wave*16 + fr;
    int sm1 = sm0 + 64;
    int wr0 = n0 + sm0; if (wr0 >= N) wr0 = N - 1;
    int wr1 = n0 + sm1; if (wr1 >= N) wr1 = N - 1;
    const __hip_bfloat16* Ag0 = A + (size_t)(m0 + sm0) * K + fq*8;
    const __hip_bfloat16* Ag1 = A + (size_t)(m0 + sm1) * K + fq*8;
    const __hip_bfloat16* Wg0 = W + (size_t)wr0 * K + fq*8;
    const __hip_bfloat16* Wg1 = W + (size_t)wr1 * K + fq*8;

    for (int k0 = 0; k0 < K; k0 += 32) {
        gload_lds16(Ag0 + k0, As + (size_t)wave*512);
        gload_lds16(Ag1 + k0, As + (size_t)(wave+4)*512);
        gload_lds16(Wg0 + k0, Bs + (size_t)wave*512);
        gload_lds16(Wg1 + k0, Bs + (size_t)(wave+4)*512);
        __syncthreads();
        bf16x8 af[4], bfr[4];
        #pragma unroll
        for (int i = 0; i < 4; ++i) {
            af[i]  = *(const bf16x8*)(As + (size_t)(wm/16 + i)*512 + lane*8);
            bfr[i] = *(const bf16x8*)(Bs + (size_t)(wn/16 + i)*512 + lane*8);
        }
        #pragma unroll
        for (int mi = 0; mi < 4; ++mi)
            #pragma unroll
            for (int ni = 0; ni < 4; ++ni)
                acc[mi][ni] = __builtin_amdgcn_mfma_f32_16x16x32_bf16(
                    af[mi], bfr[ni], acc[mi][ni], 0, 0, 0);
        __syncthreads();
    }

    #pragma unroll
    for (int ni = 0; ni < 4; ++ni) {
        int n = n0 + wn + ni*16 + fr;
        bool nok = n < N;
        float bv = (bias && nok) ? bias[n] : 0.f;
        #pragma unroll
        for (int mi = 0; mi < 4; ++mi) {
            #pragma unroll
            for (int r = 0; r < 4; ++r) {
                int m = m0 + wm + mi*16 + fq*4 + r;
                float v = acc[mi][ni][r] + bv;
                if (act) v = fmaxf(v, 0.f);
                if (nok) {
                    size_t idx = (size_t)m * N + n;
                    if (Cf) Cf[idx] = v;
                    if (Cb) Cb[idx] = __float2bfloat16(v);
                }
            }
        }
    }
}

__global__ __launch_bounds__(256) void gemm_bf16(
    const __hip_bfloat16* __restrict__ A, const __hip_bfloat16* __restrict__ W,
    const float* __restrict__ bias,
    float* __restrict__ Cf, __hip_bfloat16* __restrict__ Cb,
    int N, int K, int act)
{
    __shared__ __attribute__((aligned(16))) __hip_bfloat16 As[8*512];
    __shared__ __attribute__((aligned(16))) __hip_bfloat16 Bs[8*512];
    gemm_core128(A, W, bias, Cf, Cb, N, K, act, blockIdx.y * 128, blockIdx.x * 128, As, Bs);
}

// ---- projection GEMM + co-scheduled weight conversions --------------------
// bx < 21: 128x128 proj tile. bx >= 21: streaming f32->bf16 conversion of
// the 8 arrays NOT needed before the scan launch (58 MB hidden under GEMM).
struct F2B8 {
    const float* s[8];
    __hip_bfloat16* d[8];
    int cum[9];
};

__global__ __launch_bounds__(256, 1) void proj_conv(
    const __hip_bfloat16* __restrict__ A, const __hip_bfloat16* __restrict__ W,
    const float* __restrict__ bias, float* __restrict__ Cf, F2B8 a)
{
    __shared__ __attribute__((aligned(16))) __hip_bfloat16 As[8*512];
    __shared__ __attribute__((aligned(16))) __hip_bfloat16 Bs[8*512];
    if (blockIdx.x >= 21) {
        int cid = (blockIdx.x - 21) * 32 + blockIdx.y;   // 0..7423
        int q = cid * 256 + threadIdx.x;
        if (q >= a.cum[8]) return;
        int s = 0;
        #pragma unroll
        for (int i = 1; i < 8; ++i) s += (q >= a.cum[i]);
        int i4 = (q - a.cum[s]) * 4;
        float4 v = *(const float4*)(a.s[s] + i4);
        __hip_bfloat16* dst = a.d[s] + i4;
        dst[0] = __float2bfloat16(v.x);
        dst[1] = __float2bfloat16(v.y);
        dst[2] = __float2bfloat16(v.z);
        dst[3] = __float2bfloat16(v.w);
        return;
    }
    gemm_core128(A, W, bias, Cf, nullptr, NPROJ, DM, 0,
                 blockIdx.y * 128, blockIdx.x * 128, As, Bs);
}

// FFC1 + Bx2 in one launch
__global__ __launch_bounds__(256) void ffc1_bx_dual(
    const __hip_bfloat16* __restrict__ Aa, const __hip_bfloat16* __restrict__ Wa,
    const float* __restrict__ biasA, __hip_bfloat16* __restrict__ CbA,
    int Na, int splitX,
    const __hip_bfloat16* __restrict__ Ab, const __hip_bfloat16* __restrict__ Wb,
    float* __restrict__ CfB, int Nb, int K)
{
    __shared__ __attribute__((aligned(16))) __hip_bfloat16 As[8*512];
    __shared__ __attribute__((aligned(16))) __hip_bfloat16 Bs[8*512];
    int bx = blockIdx.x;
    if (bx < splitX)
        gemm_core128(Aa, Wa, biasA, nullptr, CbA, Na, K, 1, blockIdx.y*128, bx*128, As, Bs);
    else
        gemm_core128(Ab, Wb, nullptr, CfB, nullptr, Nb, K, 0, blockIdx.y*128, (bx-splitX)*128, As, Bs);
}

// ---------------- 64x64-tile GEMM for small-N (N=512) cases ---------------
__global__ __launch_bounds__(256) void gemm_bf16_s(
    const __hip_bfloat16* __restrict__ A, const __hip_bfloat16* __restrict__ W,
    const float* __restrict__ bias,
    float* __restrict__ Cf, __hip_bfloat16* __restrict__ Cb,
    int N, int K, int act)
{
    __shared__ __attribute__((aligned(16))) __hip_bfloat16 As[4*512];
    __shared__ __attribute__((aligned(16))) __hip_bfloat16 Bs[4*512];
    int tid = threadIdx.x;
    int wave = tid >> 6, lane = tid & 63;
    int m0 = blockIdx.y * 64, n0 = blockIdx.x * 64;
    int wm = (wave >> 1) * 32, wn = (wave & 1) * 32;
    int fr = lane & 15, fq = lane >> 4;

    f32x4 acc[2][2];
    #pragma unroll
    for (int i = 0; i < 2; ++i)
        #pragma unroll
        for (int j = 0; j < 2; ++j)
            acc[i][j] = (f32x4){0.f, 0.f, 0.f, 0.f};

    const __hip_bfloat16* Ag = A + (size_t)(m0 + wave*16 + fr) * K + fq*8;
    int wr0 = n0 + wave*16 + fr; if (wr0 >= N) wr0 = N - 1;
    const __hip_bfloat16* Wg = W + (size_t)wr0 * K + fq*8;

    for (int k0 = 0; k0 < K; k0 += 32) {
        gload_lds16(Ag + k0, As + (size_t)wave*512);
        gload_lds16(Wg + k0, Bs + (size_t)wave*512);
        __syncthreads();
        bf16x8 af[2], bfr[2];
        #pragma unroll
        for (int i = 0; i < 2; ++i)
            af[i]  = *(const bf16x8*)(As + (size_t)(wm/16 + i)*512 + lane*8);
        #pragma unroll
        for (int j = 0; j < 2; ++j)
            bfr[j] = *(const bf16x8*)(Bs + (size_t)(wn/16 + j)*512 + lane*8);
        #pragma unroll
        for (int mi = 0; mi < 2; ++mi)
            #pragma unroll
            for (int ni = 0; ni < 2; ++ni)
                acc[mi][ni] = __builtin_amdgcn_mfma_f32_16x16x32_bf16(
                    af[mi], bfr[ni], acc[mi][ni], 0, 0, 0);
        __syncthreads();
    }

    #pragma unroll
    for (int ni = 0; ni < 2; ++ni) {
        int n = n0 + wn + ni*16 + fr;
        bool nok = n < N;
        float bv = (bias && nok) ? bias[n] : 0.f;
        #pragma unroll
        for (int mi = 0; mi < 2; ++mi) {
            #pragma unroll
            for (int r = 0; r < 4; ++r) {
                int m = m0 + wm + mi*16 + fq*4 + r;
                float v = acc[mi][ni][r] + bv;
                if (act) v = fmaxf(v, 0.f);
                if (nok) {
                    size_t idx = (size_t)m * N + n;
                    if (Cf) Cf[idx] = v;
                    if (Cb) Cb[idx] = __float2bfloat16(v);
                }
            }
        }
    }
}

// ---- GRU A-GEMM: 64x128 tiles (grid 12 x 64 = 768 blocks, 3/CU) with
// fused r/z epilogue. n-regions (512 bounds) are multiples of 128 ->
// every block is region-uniform; branch on n0 only.
__global__ __launch_bounds__(256) void gemm_gruA_64(
    const __hip_bfloat16* __restrict__ A, const __hip_bfloat16* __restrict__ W,
    const float* __restrict__ Bx, const float* __restrict__ x,
    __hip_bfloat16* __restrict__ rx, float* __restrict__ z,
    float* __restrict__ A1h)
{
    __shared__ __attribute__((aligned(16))) __hip_bfloat16 As[4*512];
    __shared__ __attribute__((aligned(16))) __hip_bfloat16 Bs[8*512];
    const int K = DM;
    int tid = threadIdx.x;
    int wave = tid >> 6, lane = tid & 63;
    int m0 = blockIdx.y * 64, n0 = blockIdx.x * 128;
    int wm = (wave >> 1) * 32, wn = (wave & 1) * 64;
    int fr = lane & 15, fq = lane >> 4;

    f32x4 acc[2][4];
    #pragma unroll
    for (int i = 0; i < 2; ++i)
        #pragma unroll
        for (int j = 0; j < 4; ++j)
            acc[i][j] = (f32x4){0.f, 0.f, 0.f, 0.f};

    const __hip_bfloat16* Ag  = A + (size_t)(m0 + wave*16 + fr) * K + fq*8;
    const __hip_bfloat16* Wg0 = W + (size_t)(n0 + wave*16 + fr) * K + fq*8;
    const __hip_bfloat16* Wg1 = Wg0 + (size_t)64 * K;

    for (int k0 = 0; k0 < K; k0 += 32) {
        gload_lds16(Ag  + k0, As + (size_t)wave*512);
        gload_lds16(Wg0 + k0, Bs + (size_t)wave*512);
        gload_lds16(Wg1 + k0, Bs + (size_t)(wave+4)*512);
        __syncthreads();
        bf16x8 af[2], bfr[4];
        #pragma unroll
        for (int i = 0; i < 2; ++i)
            af[i]  = *(const bf16x8*)(As + (size_t)(wm/16 + i)*512 + lane*8);
        #pragma unroll
        for (int j = 0; j < 4; ++j)
            bfr[j] = *(const bf16x8*)(Bs + (size_t)(wn/16 + j)*512 + lane*8);
        #pragma unroll
        for (int mi = 0; mi < 2; ++mi)
            #pragma unroll
            for (int ni = 0; ni < 4; ++ni)
                acc[mi][ni] = __builtin_amdgcn_mfma_f32_16x16x32_bf16(
                    af[mi], bfr[ni], acc[mi][ni], 0, 0, 0);
        __syncthreads();
    }

    #pragma unroll
    for (int ni = 0; ni < 4; ++ni) {
        int n = n0 + wn + ni*16 + fr;
        #pragma unroll
        for (int mi = 0; mi < 2; ++mi) {
            #pragma unroll
            for (int r = 0; r < 4; ++r) {
                int m = m0 + wm + mi*16 + fq*4 + r;
                float v = acc[mi][ni][r];
                size_t mb = (size_t)m;
                if (n0 < 512) {
                    float rpre = v + Bx[mb*1024 + n];
                    rx[mb*512 + n] =
                        __float2bfloat16(sigmoidf_(rpre) * x[mb*512 + n]);
                } else if (n0 < 1024) {
                    float zpre = v + Bx[mb*1024 + n] - 2.0f;
                    z[mb*512 + (n - 512)] = sigmoidf_(zpre);
                } else {
                    A1h[mb*512 + (n - 1024)] = v;
                }
            }
        }
    }
}

// ---- GRU2 C-GEMM (64x64, N=512) with fused final gate ---------------------
__global__ __launch_bounds__(256) void gemm_gruC2_s(
    const __hip_bfloat16* __restrict__ A, const __hip_bfloat16* __restrict__ W,
    const float* __restrict__ A1h, const float* __restrict__ z,
    const float* __restrict__ x, float* __restrict__ out)
{
    __shared__ __attribute__((aligned(16))) __hip_bfloat16 As[4*512];
    __shared__ __attribute__((aligned(16))) __hip_bfloat16 Bs[4*512];
    const int K = DM;
    int tid = threadIdx.x;
    int wave = tid >> 6, lane = tid & 63;
    int m0 = blockIdx.y * 64, n0 = blockIdx.x * 64;
    int wm = (wave >> 1) * 32, wn = (wave & 1) * 32;
    int fr = lane & 15, fq = lane >> 4;

    f32x4 acc[2][2];
    #pragma unroll
    for (int i = 0; i < 2; ++i)
        #pragma unroll
        for (int j = 0; j < 2; ++j)
            acc[i][j] = (f32x4){0.f, 0.f, 0.f, 0.f};

    const __hip_bfloat16* Ag = A + (size_t)(m0 + wave*16 + fr) * K + fq*8;
    const __hip_bfloat16* Wg = W + (size_t)(n0 + wave*16 + fr) * K + fq*8;

    for (int k0 = 0; k0 < K; k0 += 32) {
        gload_lds16(Ag + k0, As + (size_t)wave*512);
        gload_lds16(Wg + k0, Bs + (size_t)wave*512);
        __syncthreads();
        bf16x8 af[2], bfr[2];
        #pragma unroll
        for (int i = 0; i < 2; ++i)
            af[i]  = *(const bf16x8*)(As + (size_t)(wm/16 + i)*512 + lane*8);
        #pragma unroll
        for (int j = 0; j < 2; ++j)
            bfr[j] = *(const bf16x8*)(Bs + (size_t)(wn/16 + j)*512 + lane*8);
        #pragma unroll
        for (int mi = 0; mi < 2; ++mi)
            #pragma unroll
            for (int ni = 0; ni < 2; ++ni)
                acc[mi][ni] = __builtin_amdgcn_mfma_f32_16x16x32_bf16(
                    af[mi], bfr[ni], acc[mi][ni], 0, 0, 0);
        __syncthreads();
    }

    #pragma unroll
    for (int ni = 0; ni < 2; ++ni) {
        int n = n0 + wn + ni*16 + fr;
        #pragma unroll
        for (int mi = 0; mi < 2; ++mi) {
            #pragma unroll
            for (int r = 0; r < 4; ++r) {
                int m = m0 + wm + mi*16 + fq*4 + r;
                size_t i = (size_t)m * 512 + n;
                float hh = tanhf(A1h[i] + acc[mi][ni][r]);
                float zz = z[i];
                out[i] = (1.0f - zz) * x[i] + zz * hh;
            }
        }
    }
}

// ---------------- chunk-parallel scans + attention + co-scheduled GEMM ----
// (R1 structure — best measured: 53.4 us. Unchanged.)
#define NCH   4
#define CHK   32
#define BNDF  (44*64)   // 44 state components per lane, comp-major

__global__ __launch_bounds__(256) void scan_attn_fused(
    const float* __restrict__ proj, const int* __restrict__ term,
    const float* __restrict__ tick, const float* __restrict__ tilde_k,
    const float* __restrict__ tilde_v, const float* __restrict__ s_prev,
    __hip_bfloat16* __restrict__ attn,
    const __hip_bfloat16* __restrict__ gA, const __hip_bfloat16* __restrict__ gW,
    float* __restrict__ gC)
{
    extern __shared__ __attribute__((aligned(16))) char smem_dyn[];
    int bid = blockIdx.x;
    if (bid >= 256) {
        __hip_bfloat16* As = (__hip_bfloat16*)smem_dyn;
        __hip_bfloat16* Bs = As + 8*512;
        int g = bid - 256;
        gemm_core128(gA, gW, nullptr, gC, nullptr, 1024, DM, 0,
                     (g >> 3) * 128, (g & 7) * 128, As, Bs);
        return;
    }

    float* bnd  = (float*)smem_dyn;            // 3 * BNDF floats (boundaries)
    float* occt = bnd + 3*BNDF;                // 128*8 cos table
    int*   flags= (int*)(occt + TT*8);         // 4 flags

    const int b = bid >> 3, h = bid & 7;
    const int tid = threadIdx.x;
    const int wv = tid >> 6, lane = tid & 63;
    const int t0 = wv * CHK;

    const float tk = tick[b];
    if (tid < 4) flags[tid] = 0;
    {
        const float PI_ = 3.14159265358979323846f;
        #pragma unroll
        for (int i = 0; i < 4; ++i) {
            int idx = tid*4 + i;                 // 1024 = 128 t x 8 r
            int t = idx >> 3, r = idx & 7;
            float w = -PI_ + (float)r * (2.0f*PI_/7.0f);
            occt[idx] = cosf((tk + (float)(t + 1)) * w);
        }
    }
    __syncthreads();

    int tmv = (lane < CHK) ? term[(size_t)(t0 + lane)*BBATCH + b] : 0;

    float fs[4], fk[8][4], fv[8], Pg[4], Pb;

    auto zero_state = [&]() {
        #pragma unroll
        for (int j = 0; j < 4; ++j) fs[j] = 0.f;
        #pragma unroll
        for (int r = 0; r < 8; ++r) {
            #pragma unroll
            for (int j = 0; j < 4; ++j) fk[r][j] = 0.f;
            fv[r] = 0.f;
        }
    };
    auto load_init = [&]() {
        float4 s4 = *(const float4*)(s_prev + ((size_t)(b*HH + h))*256 + lane*4);
        fs[0]=s4.x; fs[1]=s4.y; fs[2]=s4.z; fs[3]=s4.w;
        #pragma unroll
        for (int r = 0; r < 8; ++r) {
            float4 k4 = *(const float4*)(tilde_k + (((size_t)b*RR + r)*HH + h)*256 + lane*4);
            fk[r][0]=k4.x; fk[r][1]=k4.y; fk[r][2]=k4.z; fk[r][3]=k4.w;
            fv[r] = tilde_v[(((size_t)b*RR + r)*HH + h)*64 + lane];
        }
    };
    auto load_bnd = [&](int w) {
        const float* p = bnd + w*BNDF;
        #pragma unroll
        for (int j = 0; j < 4; ++j) fs[j] = p[j*64 + lane];
        #pragma unroll
        for (int r = 0; r < 8; ++r) {
            #pragma unroll
            for (int j = 0; j < 4; ++j) fk[r][j] = p[(4 + r*4 + j)*64 + lane];
            fv[r] = p[(36 + r)*64 + lane];
        }
    };
    auto store_bnd = [&](int w) {
        float* p = bnd + w*BNDF;
        #pragma unroll
        for (int j = 0; j < 4; ++j) p[j*64 + lane] = fs[j];
        #pragma unroll
        for (int r = 0; r < 8; ++r) {
            #pragma unroll
            for (int j = 0; j < 4; ++j) p[(4 + r*4 + j)*64 + lane] = fk[r][j];
            p[(36 + r)*64 + lane] = fv[r];
        }
    };
    auto combine = [&](int w) {   // fold true init (bnd[w]) into local state
        const float* p = bnd + w*BNDF;
        #pragma unroll
        for (int j = 0; j < 4; ++j) fs[j] = fmaf(Pg[j], p[j*64 + lane], fs[j]);
        #pragma unroll
        for (int r = 0; r < 8; ++r) {
            #pragma unroll
            for (int j = 0; j < 4; ++j)
                fk[r][j] = fmaf(Pg[j], p[(4 + r*4 + j)*64 + lane], fk[r][j]);
            fv[r] = fmaf(Pb, p[(36 + r)*64 + lane], fv[r]);
        }
    };

    struct Raw { float k, q, v, be, ga; float4 P1, P2, P3; };
    auto load_raw = [&](int t, Raw& rw) {
        const float* prow = proj + (size_t)(t*BBATCH + b) * NPROJ;
        const float* p5 = prow + h*320;
        rw.k  = p5[lane];
        rw.q  = p5[64  + lane];
        rw.v  = p5[128 + lane];
        rw.be = p5[192 + lane];
        rw.ga = p5[256 + lane];
        const float* pp = prow + KQV + h*12;      // wave-uniform -> s_load
        rw.P1 = *(const float4*)(pp);
        rw.P2 = *(const float4*)(pp + 4);
        rw.P3 = *(const float4*)(pp + 8);
    };

    auto sweep = [&](bool out) {
        Pg[0]=Pg[1]=Pg[2]=Pg[3]=1.f; Pb=1.f;
        Raw cur, nxt;
        load_raw(t0, cur);
        for (int i = 0; i < CHK; ++i) {
            const int t = t0 + i;
            if (i + 1 < CHK) load_raw(t + 1, nxt);
            const int tm = __builtin_amdgcn_readlane(tmv, i);
            const float mask = 1.0f - (float)tm;
            float kr = fmaxf(cur.k, 0.f);
            float sg = sigmoidf_(cur.ga);
            float sb = sigmoidf_(cur.be);
            float vg = cur.v * sb;
            float db = (1.f - sb) * mask;
            float p1a[4] = {cur.P1.x, cur.P1.y, cur.P1.z, cur.P1.w};
            float p3a[4] = {cur.P3.x, cur.P3.y, cur.P3.z, cur.P3.w};
            float kg[4], dg[4];
            #pragma unroll
            for (int j = 0; j < 4; ++j) {
                float gexp = sg * sigmoidf_(p3a[j]);
                kg[j] = kr * fmaxf(p1a[j], 0.f) * gexp;
                dg[j] = (1.f - gexp) * mask;
            }
            float occ[8];
            {
                float4 o0 = *(const float4*)(occt + t*8);
                float4 o1 = *(const float4*)(occt + t*8 + 4);
                occ[0]=o0.x; occ[1]=o0.y; occ[2]=o0.z; occ[3]=o0.w;
                occ[4]=o1.x; occ[5]=o1.y; occ[6]=o1.z; occ[7]=o1.w;
            }
            #pragma unroll
            for (int j = 0; j < 4; ++j) {
                fs[j] = fmaf(dg[j], fs[j], kg[j]);
                Pg[j] *= dg[j];
            }
            #pragma unroll
            for (int r = 0; r < 8; ++r) {
                #pragma unroll
                for (int j = 0; j < 4; ++j)
                    fk[r][j] = fmaf(dg[j], fk[r][j], kg[j]*occ[r]);
                fv[r] = fmaf(db, fv[r], vg*occ[r]);
            }
            Pb *= db;
            if (out) {
                float qr = fmaxf(cur.q, 0.f);
                float p2a[4] = {cur.P2.x, cur.P2.y, cur.P2.z, cur.P2.w};
                float qe[4];
                #pragma unroll
                for (int j = 0; j < 4; ++j) qe[j] = qr * fmaxf(p2a[j], 0.f);
                float snorm = fs[0]*qe[0] + fs[1]*qe[1] + fs[2]*qe[2] + fs[3]*qe[3];
                float nrm_u = wave_sum_u(snorm);
                float kdq_u[8];
                #pragma unroll
                for (int r = 0; r < 8; ++r) {
                    float kdq = fk[r][0]*qe[0] + fk[r][1]*qe[1]
                              + fk[r][2]*qe[2] + fk[r][3]*qe[3];
                    kdq_u[r] = wave_sum_u(kdq);
                }
                float kv = 0.f;
                #pragma unroll
                for (int r = 0; r < 8; ++r) kv = fmaf(fv[r], kdq_u[r], kv);
                attn[(size_t)(t*BBATCH + b)*DM + h*64 + lane] =
                    __float2bfloat16(kv / (16.f * (nrm_u + 1e-6f)));
            }
            cur = nxt;
        }
    };

    // ---- pass 1: parallel local scans (chunk 3 skips: it never posts) ----
    if (wv < NCH - 1) {
        if (wv == 0) load_init(); else zero_state();
        sweep(false);
        if (wv > 0) {
            while (__hip_atomic_load(&flags[wv-1], __ATOMIC_ACQUIRE,
                                     __HIP_MEMORY_SCOPE_WORKGROUP) == 0)
                __builtin_amdgcn_s_sleep(1);
            combine(wv - 1);
        }
        store_bnd(wv);
        if (lane == 0)
            __hip_atomic_store(&flags[wv], 1, __ATOMIC_RELEASE,
                               __HIP_MEMORY_SCOPE_WORKGROUP);
    }

    // ---- pass 2: replay from exact chunk-start state, with outputs ------
    if (wv == 0) {
        load_init();
    } else {
        while (__hip_atomic_load(&flags[wv-1], __ATOMIC_ACQUIRE,
                                 __HIP_MEMORY_SCOPE_WORKGROUP) == 0)
            __builtin_amdgcn_s_sleep(1);
        load_bnd(wv - 1);
    }
    sweep(true);
}

// GRU1 final fused with LN2 (A1h 512-stride)
__global__ __launch_bounds__(256) void gru_final_ln(
    const float* __restrict__ A1h, const float* __restrict__ C2,
    const float* __restrict__ z, const float* __restrict__ x,
    const float* __restrict__ g, const float* __restrict__ bta,
    float* __restrict__ g1, __hip_bfloat16* __restrict__ g1b,
    __hip_bfloat16* __restrict__ fib)
{
    int row = blockIdx.x;
    int tid = threadIdx.x;
    size_t base = (size_t)row * DM;
    float2 c2v = ((const float2*)(C2 + base))[tid];
    float2 zv  = ((const float2*)(z  + base))[tid];
    float2 xv  = ((const float2*)(x  + base))[tid];
    float2 av  = ((const float2*)(A1h + base))[tid];
    float h0 = tanhf(av.x + c2v.x);
    float h1 = tanhf(av.y + c2v.y);
    float2 v;
    v.x = (1.0f - zv.x) * xv.x + zv.x * h0;
    v.y = (1.0f - zv.y) * xv.y + zv.y * h1;
    ((float2*)(g1 + base))[tid] = v;
    g1b[base + 2*tid+0] = __float2bfloat16(v.x);
    g1b[base + 2*tid+1] = __float2bfloat16(v.y);

    float s = v.x + v.y;
    #pragma unroll
    for (int off = 32; off; off >>= 1) s += __shfl_down(s, off);
    __shared__ float red[8];
    int wid = tid >> 6, lane = tid & 63;
    if (lane == 0) red[wid] = s;
    __syncthreads();
    if (tid == 0) red[0] = (red[0] + red[1] + red[2] + red[3]) * (1.0f / DM);
    __syncthreads();
    float mean = red[0];
    float dx = v.x - mean, dy = v.y - mean;
    float sq = dx*dx + dy*dy;
    #pragma unroll
    for (int off = 32; off; off >>= 1) sq += __shfl_down(sq, off);
    if (lane == 0) red[4 + wid] = sq;
    __syncthreads();
    if (tid == 0) red[1] = rsqrtf((red[4]+red[5]+red[6]+red[7]) * (1.0f/DM) + 1e-5f);
    __syncthreads();
    float rstd = red[1];
    float2 gg = ((const float2*)g)[tid];
    float2 bb = ((const float2*)bta)[tid];
    fib[base + 2*tid+0] = __float2bfloat16(dx * rstd * gg.x + bb.x);
    fib[base + 2*tid+1] = __float2bfloat16(dy * rstd * gg.y + bb.y);
}

// ---------------- launch --------------------------------------------------
extern "C" void kernel_launch(void* const* d_in, const int* in_sizes, int n_in,
                              void* d_out, int out_size, void* d_ws, size_t ws_size,
                              hipStream_t stream)
{
    const float* inputs = (const float*)d_in[0];
    const int*   term   = (const int*)  d_in[1];
    const float* tilde_k= (const float*)d_in[2];
    const float* tilde_v= (const float*)d_in[3];
    const float* s_prev = (const float*)d_in[4];
    const float* tick   = (const float*)d_in[5];
    const float* w_proj = (const float*)d_in[6];
    const float* b_proj = (const float*)d_in[7];
    const float* w_attn = (const float*)d_in[8];
    const float* b_attn = (const float*)d_in[9];
    const float* ln1_g  = (const float*)d_in[10];
    const float* ln1_b  = (const float*)d_in[11];
    const float* ln2_g  = (const float*)d_in[12];
    const float* ln2_b  = (const float*)d_in[13];
    const float* gru1_w = (const float*)d_in[14];
    const float* gru1_u = (const float*)d_in[15];
    const float* gru2_w = (const float*)d_in[16];
    const float* gru2_u = (const float*)d_in[17];
    const float* ffc_w1 = (const float*)d_in[18];
    const float* ffc_b1 = (const float*)d_in[19];
    const float* ffc_w2 = (const float*)d_in[20];
    const float* ffc_b2 = (const float*)d_in[21];
    float* out = (float*)d_out;
    float* ws  = (float*)d_ws;

    // ---- f32 region (floats) ----
    float* proj = ws;                       // 4096x2656 (dead after scan)
    float* A1h  = ws;                       // 4096x512  (overlays proj)
    float* C2   = ws + 10878976;            // 4096x512
    float* zb   = ws + 12976128;            // 4096x512
    float* g1   = ws + 15073280;            // 4096x512
    // ---- bf16 region ----
    __hip_bfloat16* bb = (__hip_bfloat16*)(ws + 17170432);
    __hip_bfloat16* wp_bf  = bb + 0;          // 2656x512
    __hip_bfloat16* wat_bf = bb + 1359872;    // 512x512
    __hip_bfloat16* g1w_bf = bb + 1622016;    // 3x512x512
    __hip_bfloat16* g1u_bf = bb + 2408448;
    __hip_bfloat16* g2w_bf = bb + 3194880;
    __hip_bfloat16* g2u_bf = bb + 3981312;
    __hip_bfloat16* fw1_bf = bb + 4767744;    // 2048x512
    __hip_bfloat16* fw2_bf = bb + 5816320;    // 512x2048
    __hip_bfloat16* in_bf  = bb + 6864896;    // 4096x512
    __hip_bfloat16* xn_bf  = bb + 8962048;
    __hip_bfloat16* at_bf  = bb + 11059200;
    __hip_bfloat16* y1_bf  = bb + 13156352;
    __hip_bfloat16* rx_bf  = bb + 15253504;
    __hip_bfloat16* fi_bf  = bb + 17350656;
    __hip_bfloat16* mid_bf = bb + 19447808;   // 4096x2048
    __hip_bfloat16* fo_bf  = bb + 27836416;
    __hip_bfloat16* g1_bf  = bb + 29933568;
    // Bx after bf16 region — never overlaps proj.
    float* Bx = ws + 33185792;   // 4096x1024

    dim3 blk(256);

    // 1. critical-path conversions only: w_proj -> bf16 + LN1 -> xn_bf
    f2b_wp_ln<<<1328 + MM, blk, 0, stream>>>(w_proj, wp_bf, inputs, ln1_g, ln1_b, xn_bf);

    // 2. projection GEMM + co-scheduled conversion of remaining 8 arrays
    F2B8 fa;
    const float* srcs[8] = {w_attn, gru1_w, gru1_u, gru2_w, gru2_u,
                            ffc_w1, ffc_w2, inputs};
    __hip_bfloat16* dsts[8] = {wat_bf, g1w_bf, g1u_bf, g2w_bf, g2u_bf,
                               fw1_bf, fw2_bf, in_bf};
    int quads[8] = {65536, 196608, 196608, 196608, 196608,
                    262144, 262144, 524288};
    int cum = 0;
    for (int i = 0; i < 8; ++i) { fa.s[i] = srcs[i]; fa.d[i] = dsts[i]; fa.cum[i] = cum; cum += quads[i]; }
    fa.cum[8] = cum;   // 1,900,544 quads = 7424 blocks = 232*32
    proj_conv<<<dim3(21 + 232, 32), blk, 0, stream>>>(xn_bf, wp_bf, b_proj, proj, fa);

    // 3. chunk-parallel scans + attention + GRU1's Bx GEMM
    size_t dyn = (size_t)(3*BNDF + TT*8 + 4) * 4;   // ~37.9 KB (>= gemm's 16 KB)
    scan_attn_fused<<<512, blk, dyn, stream>>>(proj, term, tick, tilde_k, tilde_v,
                                               s_prev, at_bf, in_bf, g1u_bf, Bx);

    // 4. attn out-proj (+relu) — 64x64 tiles
    gemm_bf16_s<<<dim3(8, 64), blk, 0, stream>>>(at_bf, wat_bf, b_attn, nullptr, y1_bf, DM, DM, 1);

    // 5. GRU1: A-GEMM (64x128, fused r/z); C-GEMM; final+LN2
    gemm_gruA_64<<<dim3(12, 64), blk, 0, stream>>>(y1_bf, g1w_bf, Bx, inputs, rx_bf, zb, A1h);
    gemm_bf16_s<<<dim3(8, 64), blk, 0, stream>>>(rx_bf, g1u_bf + 2*DM*DM, nullptr, C2, nullptr, DM, DM, 0);
    gru_final_ln<<<MM, blk, 0, stream>>>(A1h, C2, zb, inputs, ln2_g, ln2_b, g1, g1_bf, fi_bf);

    // 6. FFC1 + GRU2's Bx GEMM (one launch)
    ffc1_bx_dual<<<dim3(24, 32), blk, 0, stream>>>(fi_bf, fw1_bf, ffc_b1, mid_bf,
                                                   2048, 16,
                                                   g1_bf, g2u_bf, Bx, 1024, DM);

    // 7. FFC2 (+relu) — 64x64 tiles
    gemm_bf16_s<<<dim3(8, 64), blk, 0, stream>>>(mid_bf, fw2_bf, ffc_b2, nullptr, fo_bf, DM, 2048, 1);

    // 8. GRU2: A-GEMM (64x128, fused r/z); C-GEMM (fused final, writes out)
    gemm_gruA_64<<<dim3(12, 64), blk, 0, stream>>>(fo_bf, g2w_bf, Bx, g1, rx_bf, zb, A1h);
    gemm_gruC2_s<<<dim3(8, 64), blk, 0, stream>>>(rx_bf, g2u_bf + 2*DM*DM, A1h, zb, g1, out);
}

// Round 11
// 383.689 us; speedup vs baseline: 1.0767x; 1.0767x over previous
//
#include <hip/hip_runtime.h>
#include <hip/hip_bf16.h>
#include <math.h>

#define DM   512
#define HH   8
#define RR   8
#define TT   128
#define BBATCH 32
#define MM   (TT*BBATCH)     // 4096 rows
#define NPROJ 2656
#define KQV  2560

typedef __attribute__((ext_vector_type(8))) short bf16x8;
typedef __attribute__((ext_vector_type(4))) float f32x4;

__device__ __forceinline__ float sigmoidf_(float x) {
    return 1.0f / (1.0f + __expf(-x));
}

__device__ __forceinline__ void gload_lds16(const void* g, void* l) {
    __builtin_amdgcn_global_load_lds(
        (const __attribute__((address_space(1))) unsigned int*)g,
        (__attribute__((address_space(3))) unsigned int*)l, 16, 0, 0);
}

// ---- DPP wave64 sum -> uniform value --------------------------------------
template<int CTRL, int RMASK>
__device__ __forceinline__ float dpp_add_(float x) {
    union { float f; int i; } a, b;
    a.f = x;
    b.i = __builtin_amdgcn_update_dpp(0, a.i, CTRL, RMASK, 0xf, true);
    return x + b.f;
}
__device__ __forceinline__ float wave_sum_u(float x) {
    x = dpp_add_<0x111, 0xf>(x);
    x = dpp_add_<0x112, 0xf>(x);
    x = dpp_add_<0x114, 0xf>(x);
    x = dpp_add_<0x118, 0xf>(x);
    x = dpp_add_<0x142, 0xa>(x);
    x = dpp_add_<0x143, 0xc>(x);
    union { float f; int i; } s, t;
    s.f = x;
    t.i = __builtin_amdgcn_readlane(s.i, 63);
    return t.f;
}

// ---------------- merged f32->bf16 conversions + LN1 (one launch) ---------
struct F2B9 {
    const float* s[9];
    __hip_bfloat16* d[9];
    int cum[10];
};

__global__ __launch_bounds__(256) void f2b_ln_all(F2B9 a,
    const float* __restrict__ x, const float* __restrict__ g,
    const float* __restrict__ b, __hip_bfloat16* __restrict__ lnout)
{
    if (blockIdx.x < 8752) {
        int q = blockIdx.x * 256 + threadIdx.x;
        if (q >= a.cum[9]) return;
        int s = 0;
        #pragma unroll
        for (int i = 1; i < 9; ++i) s += (q >= a.cum[i]);
        int i4 = (q - a.cum[s]) * 4;
        float4 v = *(const float4*)(a.s[s] + i4);
        __hip_bfloat16* dst = a.d[s] + i4;
        dst[0] = __float2bfloat16(v.x);
        dst[1] = __float2bfloat16(v.y);
        dst[2] = __float2bfloat16(v.z);
        dst[3] = __float2bfloat16(v.w);
        return;
    }
    int row = blockIdx.x - 8752;
    int tid = threadIdx.x;
    const float* xr = x + (size_t)row * DM;
    float2 v = ((const float2*)xr)[tid];
    float s = v.x + v.y;
    #pragma unroll
    for (int off = 32; off; off >>= 1) s += __shfl_down(s, off);
    __shared__ float red[8];
    int wid = tid >> 6, lane = tid & 63;
    if (lane == 0) red[wid] = s;
    __syncthreads();
    if (tid == 0) red[0] = (red[0] + red[1] + red[2] + red[3]) * (1.0f / DM);
    __syncthreads();
    float mean = red[0];
    float dx = v.x - mean, dy = v.y - mean;
    float sq = dx*dx + dy*dy;
    #pragma unroll
    for (int off = 32; off; off >>= 1) sq += __shfl_down(sq, off);
    if (lane == 0) red[4 + wid] = sq;
    __syncthreads();
    if (tid == 0) red[1] = rsqrtf((red[4]+red[5]+red[6]+red[7]) * (1.0f/DM) + 1e-5f);
    __syncthreads();
    float rstd = red[1];
    float2 gg = ((const float2*)g)[tid];
    float2 bb = ((const float2*)b)[tid];
    __hip_bfloat16* orow = lnout + (size_t)row * DM;
    orow[2*tid+0] = __float2bfloat16(dx * rstd * gg.x + bb.x);
    orow[2*tid+1] = __float2bfloat16(dy * rstd * gg.y + bb.y);
}

// ---------------- bf16 MFMA GEMM core: 128x128 tile, BK=32 ----------------
__device__ __forceinline__ void gemm_core128(
    const __hip_bfloat16* __restrict__ A, const __hip_bfloat16* __restrict__ W,
    const float* __restrict__ bias,
    float* __restrict__ Cf, __hip_bfloat16* __restrict__ Cb,
    int N, int K, int act, int m0, int n0,
    __hip_bfloat16* As, __hip_bfloat16* Bs)
{
    int tid = threadIdx.x;
    int wave = tid >> 6, lane = tid & 63;
    int wm = (wave >> 1) * 64, wn = (wave & 1) * 64;
    int fr = lane & 15, fq = lane >> 4;

    f32x4 acc[4][4];
    #pragma unroll
    for (int i = 0; i < 4; ++i)
        #pragma unroll
        for (int j = 0; j < 4; ++j)
            acc[i][j] = (f32x4){0.f, 0.f, 0.f, 0.f};

    int sm0 = wave*16 + fr;
    int sm1 = sm0 + 64;
    int wr0 = n0 + sm0; if (wr0 >= N) wr0 = N - 1;
    int wr1 = n0 + sm1; if (wr1 >= N) wr1 = N - 1;
    const __hip_bfloat16* Ag0 = A + (size_t)(m0 + sm0) * K + fq*8;
    const __hip_bfloat16* Ag1 = A + (size_t)(m0 + sm1) * K + fq*8;
    const __hip_bfloat16* Wg0 = W + (size_t)wr0 * K + fq*8;
    const __hip_bfloat16* Wg1 = W + (size_t)wr1 * K + fq*8;

    for (int k0 = 0; k0 < K; k0 += 32) {
        gload_lds16(Ag0 + k0, As + (size_t)wave*512);
        gload_lds16(Ag1 + k0, As + (size_t)(wave+4)*512);
        gload_lds16(Wg0 + k0, Bs + (size_t)wave*512);
        gload_lds16(Wg1 + k0, Bs + (size_t)(wave+4)*512);
        __syncthreads();
        bf16x8 af[4], bfr[4];
        #pragma unroll
        for (int i = 0; i < 4; ++i) {
            af[i]  = *(const bf16x8*)(As + (size_t)(wm/16 + i)*512 + lane*8);
            bfr[i] = *(const bf16x8*)(Bs + (size_t)(wn/16 + i)*512 + lane*8);
        }
        #pragma unroll
        for (int mi = 0; mi < 4; ++mi)
            #pragma unroll
            for (int ni = 0; ni < 4; ++ni)
                acc[mi][ni] = __builtin_amdgcn_mfma_f32_16x16x32_bf16(
                    af[mi], bfr[ni], acc[mi][ni], 0, 0, 0);
        __syncthreads();
    }

    #pragma unroll
    for (int ni = 0; ni < 4; ++ni) {
        int n = n0 + wn + ni*16 + fr;
        bool nok = n < N;
        float bv = (bias && nok) ? bias[n] : 0.f;
        #pragma unroll
        for (int mi = 0; mi < 4; ++mi) {
            #pragma unroll
            for (int r = 0; r < 4; ++r) {
                int m = m0 + wm + mi*16 + fq*4 + r;
                float v = acc[mi][ni][r] + bv;
                if (act) v = fmaxf(v, 0.f);
                if (nok) {
                    size_t idx = (size_t)m * N + n;
                    if (Cf) Cf[idx] = v;
                    if (Cb) Cb[idx] = __float2bfloat16(v);
                }
            }
        }
    }
}

__global__ __launch_bounds__(256) void gemm_bf16(
    const __hip_bfloat16* __restrict__ A, const __hip_bfloat16* __restrict__ W,
    const float* __restrict__ bias,
    float* __restrict__ Cf, __hip_bfloat16* __restrict__ Cb,
    int N, int K, int act)
{
    __shared__ __attribute__((aligned(16))) __hip_bfloat16 As[8*512];
    __shared__ __attribute__((aligned(16))) __hip_bfloat16 Bs[8*512];
    gemm_core128(A, W, bias, Cf, Cb, N, K, act, blockIdx.y * 128, blockIdx.x * 128, As, Bs);
}

// FFC1 + Bx2 in one launch
__global__ __launch_bounds__(256) void ffc1_bx_dual(
    const __hip_bfloat16* __restrict__ Aa, const __hip_bfloat16* __restrict__ Wa,
    const float* __restrict__ biasA, __hip_bfloat16* __restrict__ CbA,
    int Na, int splitX,
    const __hip_bfloat16* __restrict__ Ab, const __hip_bfloat16* __restrict__ Wb,
    float* __restrict__ CfB, int Nb, int K)
{
    __shared__ __attribute__((aligned(16))) __hip_bfloat16 As[8*512];
    __shared__ __attribute__((aligned(16))) __hip_bfloat16 Bs[8*512];
    int bx = blockIdx.x;
    if (bx < splitX)
        gemm_core128(Aa, Wa, biasA, nullptr, CbA, Na, K, 1, blockIdx.y*128, bx*128, As, Bs);
    else
        gemm_core128(Ab, Wb, nullptr, CfB, nullptr, Nb, K, 0, blockIdx.y*128, (bx-splitX)*128, As, Bs);
}

// ---------------- 64x64-tile GEMM for small-N (N=512) cases ---------------
__global__ __launch_bounds__(256) void gemm_bf16_s(
    const __hip_bfloat16* __restrict__ A, const __hip_bfloat16* __restrict__ W,
    const float* __restrict__ bias,
    float* __restrict__ Cf, __hip_bfloat16* __restrict__ Cb,
    int N, int K, int act)
{
    __shared__ __attribute__((aligned(16))) __hip_bfloat16 As[4*512];
    __shared__ __attribute__((aligned(16))) __hip_bfloat16 Bs[4*512];
    int tid = threadIdx.x;
    int wave = tid >> 6, lane = tid & 63;
    int m0 = blockIdx.y * 64, n0 = blockIdx.x * 64;
    int wm = (wave >> 1) * 32, wn = (wave & 1) * 32;
    int fr = lane & 15, fq = lane >> 4;

    f32x4 acc[2][2];
    #pragma unroll
    for (int i = 0; i < 2; ++i)
        #pragma unroll
        for (int j = 0; j < 2; ++j)
            acc[i][j] = (f32x4){0.f, 0.f, 0.f, 0.f};

    const __hip_bfloat16* Ag = A + (size_t)(m0 + wave*16 + fr) * K + fq*8;
    int wr0 = n0 + wave*16 + fr; if (wr0 >= N) wr0 = N - 1;
    const __hip_bfloat16* Wg = W + (size_t)wr0 * K + fq*8;

    for (int k0 = 0; k0 < K; k0 += 32) {
        gload_lds16(Ag + k0, As + (size_t)wave*512);
        gload_lds16(Wg + k0, Bs + (size_t)wave*512);
        __syncthreads();
        bf16x8 af[2], bfr[2];
        #pragma unroll
        for (int i = 0; i < 2; ++i)
            af[i]  = *(const bf16x8*)(As + (size_t)(wm/16 + i)*512 + lane*8);
        #pragma unroll
        for (int j = 0; j < 2; ++j)
            bfr[j] = *(const bf16x8*)(Bs + (size_t)(wn/16 + j)*512 + lane*8);
        #pragma unroll
        for (int mi = 0; mi < 2; ++mi)
            #pragma unroll
            for (int ni = 0; ni < 2; ++ni)
                acc[mi][ni] = __builtin_amdgcn_mfma_f32_16x16x32_bf16(
                    af[mi], bfr[ni], acc[mi][ni], 0, 0, 0);
        __syncthreads();
    }

    #pragma unroll
    for (int ni = 0; ni < 2; ++ni) {
        int n = n0 + wn + ni*16 + fr;
        bool nok = n < N;
        float bv = (bias && nok) ? bias[n] : 0.f;
        #pragma unroll
        for (int mi = 0; mi < 2; ++mi) {
            #pragma unroll
            for (int r = 0; r < 4; ++r) {
                int m = m0 + wm + mi*16 + fq*4 + r;
                float v = acc[mi][ni][r] + bv;
                if (act) v = fmaxf(v, 0.f);
                if (nok) {
                    size_t idx = (size_t)m * N + n;
                    if (Cf) Cf[idx] = v;
                    if (Cb) Cb[idx] = __float2bfloat16(v);
                }
            }
        }
    }
}

// ---- GRU A-GEMM: 64x128 tiles (grid 12 x 64 = 768 blocks, 3/CU) with
// fused r/z epilogue. n-regions (512 bounds) are multiples of 128 ->
// every block is region-uniform; branch on n0 only.
__global__ __launch_bounds__(256) void gemm_gruA_64(
    const __hip_bfloat16* __restrict__ A, const __hip_bfloat16* __restrict__ W,
    const float* __restrict__ Bx, const float* __restrict__ x,
    __hip_bfloat16* __restrict__ rx, float* __restrict__ z,
    float* __restrict__ A1h)
{
    __shared__ __attribute__((aligned(16))) __hip_bfloat16 As[4*512];
    __shared__ __attribute__((aligned(16))) __hip_bfloat16 Bs[8*512];
    const int K = DM;
    int tid = threadIdx.x;
    int wave = tid >> 6, lane = tid & 63;
    int m0 = blockIdx.y * 64, n0 = blockIdx.x * 128;
    int wm = (wave >> 1) * 32, wn = (wave & 1) * 64;
    int fr = lane & 15, fq = lane >> 4;

    f32x4 acc[2][4];
    #pragma unroll
    for (int i = 0; i < 2; ++i)
        #pragma unroll
        for (int j = 0; j < 4; ++j)
            acc[i][j] = (f32x4){0.f, 0.f, 0.f, 0.f};

    const __hip_bfloat16* Ag  = A + (size_t)(m0 + wave*16 + fr) * K + fq*8;
    const __hip_bfloat16* Wg0 = W + (size_t)(n0 + wave*16 + fr) * K + fq*8;
    const __hip_bfloat16* Wg1 = Wg0 + (size_t)64 * K;

    for (int k0 = 0; k0 < K; k0 += 32) {
        gload_lds16(Ag  + k0, As + (size_t)wave*512);
        gload_lds16(Wg0 + k0, Bs + (size_t)wave*512);
        gload_lds16(Wg1 + k0, Bs + (size_t)(wave+4)*512);
        __syncthreads();
        bf16x8 af[2], bfr[4];
        #pragma unroll
        for (int i = 0; i < 2; ++i)
            af[i]  = *(const bf16x8*)(As + (size_t)(wm/16 + i)*512 + lane*8);
        #pragma unroll
        for (int j = 0; j < 4; ++j)
            bfr[j] = *(const bf16x8*)(Bs + (size_t)(wn/16 + j)*512 + lane*8);
        #pragma unroll
        for (int mi = 0; mi < 2; ++mi)
            #pragma unroll
            for (int ni = 0; ni < 4; ++ni)
                acc[mi][ni] = __builtin_amdgcn_mfma_f32_16x16x32_bf16(
                    af[mi], bfr[ni], acc[mi][ni], 0, 0, 0);
        __syncthreads();
    }

    #pragma unroll
    for (int ni = 0; ni < 4; ++ni) {
        int n = n0 + wn + ni*16 + fr;
        #pragma unroll
        for (int mi = 0; mi < 2; ++mi) {
            #pragma unroll
            for (int r = 0; r < 4; ++r) {
                int m = m0 + wm + mi*16 + fq*4 + r;
                float v = acc[mi][ni][r];
                size_t mb = (size_t)m;
                if (n0 < 512) {
                    float rpre = v + Bx[mb*1024 + n];
                    rx[mb*512 + n] =
                        __float2bfloat16(sigmoidf_(rpre) * x[mb*512 + n]);
                } else if (n0 < 1024) {
                    float zpre = v + Bx[mb*1024 + n] - 2.0f;
                    z[mb*512 + (n - 512)] = sigmoidf_(zpre);
                } else {
                    A1h[mb*512 + (n - 1024)] = v;
                }
            }
        }
    }
}

// ---- GRU2 C-GEMM (64x64, N=512) with fused final gate ---------------------
__global__ __launch_bounds__(256) void gemm_gruC2_s(
    const __hip_bfloat16* __restrict__ A, const __hip_bfloat16* __restrict__ W,
    const float* __restrict__ A1h, const float* __restrict__ z,
    const float* __restrict__ x, float* __restrict__ out)
{
    __shared__ __attribute__((aligned(16))) __hip_bfloat16 As[4*512];
    __shared__ __attribute__((aligned(16))) __hip_bfloat16 Bs[4*512];
    const int K = DM;
    int tid = threadIdx.x;
    int wave = tid >> 6, lane = tid & 63;
    int m0 = blockIdx.y * 64, n0 = blockIdx.x * 64;
    int wm = (wave >> 1) * 32, wn = (wave & 1) * 32;
    int fr = lane & 15, fq = lane >> 4;

    f32x4 acc[2][2];
    #pragma unroll
    for (int i = 0; i < 2; ++i)
        #pragma unroll
        for (int j = 0; j < 2; ++j)
            acc[i][j] = (f32x4){0.f, 0.f, 0.f, 0.f};

    const __hip_bfloat16* Ag = A + (size_t)(m0 + wave*16 + fr) * K + fq*8;
    const __hip_bfloat16* Wg = W + (size_t)(n0 + wave*16 + fr) * K + fq*8;

    for (int k0 = 0; k0 < K; k0 += 32) {
        gload_lds16(Ag + k0, As + (size_t)wave*512);
        gload_lds16(Wg + k0, Bs + (size_t)wave*512);
        __syncthreads();
        bf16x8 af[2], bfr[2];
        #pragma unroll
        for (int i = 0; i < 2; ++i)
            af[i]  = *(const bf16x8*)(As + (size_t)(wm/16 + i)*512 + lane*8);
        #pragma unroll
        for (int j = 0; j < 2; ++j)
            bfr[j] = *(const bf16x8*)(Bs + (size_t)(wn/16 + j)*512 + lane*8);
        #pragma unroll
        for (int mi = 0; mi < 2; ++mi)
            #pragma unroll
            for (int ni = 0; ni < 2; ++ni)
                acc[mi][ni] = __builtin_amdgcn_mfma_f32_16x16x32_bf16(
                    af[mi], bfr[ni], acc[mi][ni], 0, 0, 0);
        __syncthreads();
    }

    #pragma unroll
    for (int ni = 0; ni < 2; ++ni) {
        int n = n0 + wn + ni*16 + fr;
        #pragma unroll
        for (int mi = 0; mi < 2; ++mi) {
            #pragma unroll
            for (int r = 0; r < 4; ++r) {
                int m = m0 + wm + mi*16 + fq*4 + r;
                size_t i = (size_t)m * 512 + n;
                float hh = tanhf(A1h[i] + acc[mi][ni][r]);
                float zz = z[i];
                out[i] = (1.0f - zz) * x[i] + zz * hh;
            }
        }
    }
}

// ---------------- chunk-parallel scans + attention + co-scheduled GEMM ----
// (R1 structure — best measured: 53.4 us. Unchanged.)
#define NCH   4
#define CHK   32
#define BNDF  (44*64)   // 44 state components per lane, comp-major

__global__ __launch_bounds__(256) void scan_attn_fused(
    const float* __restrict__ proj, const int* __restrict__ term,
    const float* __restrict__ tick, const float* __restrict__ tilde_k,
    const float* __restrict__ tilde_v, const float* __restrict__ s_prev,
    __hip_bfloat16* __restrict__ attn,
    const __hip_bfloat16* __restrict__ gA, const __hip_bfloat16* __restrict__ gW,
    float* __restrict__ gC)
{
    extern __shared__ __attribute__((aligned(16))) char smem_dyn[];
    int bid = blockIdx.x;
    if (bid >= 256) {
        __hip_bfloat16* As = (__hip_bfloat16*)smem_dyn;
        __hip_bfloat16* Bs = As + 8*512;
        int g = bid - 256;
        gemm_core128(gA, gW, nullptr, gC, nullptr, 1024, DM, 0,
                     (g >> 3) * 128, (g & 7) * 128, As, Bs);
        return;
    }

    float* bnd  = (float*)smem_dyn;            // 3 * BNDF floats (boundaries)
    float* occt = bnd + 3*BNDF;                // 128*8 cos table
    int*   flags= (int*)(occt + TT*8);         // 4 flags

    const int b = bid >> 3, h = bid & 7;
    const int tid = threadIdx.x;
    const int wv = tid >> 6, lane = tid & 63;
    const int t0 = wv * CHK;

    const float tk = tick[b];
    if (tid < 4) flags[tid] = 0;
    {
        const float PI_ = 3.14159265358979323846f;
        #pragma unroll
        for (int i = 0; i < 4; ++i) {
            int idx = tid*4 + i;                 // 1024 = 128 t x 8 r
            int t = idx >> 3, r = idx & 7;
            float w = -PI_ + (float)r * (2.0f*PI_/7.0f);
            occt[idx] = cosf((tk + (float)(t + 1)) * w);
        }
    }
    __syncthreads();

    int tmv = (lane < CHK) ? term[(size_t)(t0 + lane)*BBATCH + b] : 0;

    float fs[4], fk[8][4], fv[8], Pg[4], Pb;

    auto zero_state = [&]() {
        #pragma unroll
        for (int j = 0; j < 4; ++j) fs[j] = 0.f;
        #pragma unroll
        for (int r = 0; r < 8; ++r) {
            #pragma unroll
            for (int j = 0; j < 4; ++j) fk[r][j] = 0.f;
            fv[r] = 0.f;
        }
    };
    auto load_init = [&]() {
        float4 s4 = *(const float4*)(s_prev + ((size_t)(b*HH + h))*256 + lane*4);
        fs[0]=s4.x; fs[1]=s4.y; fs[2]=s4.z; fs[3]=s4.w;
        #pragma unroll
        for (int r = 0; r < 8; ++r) {
            float4 k4 = *(const float4*)(tilde_k + (((size_t)b*RR + r)*HH + h)*256 + lane*4);
            fk[r][0]=k4.x; fk[r][1]=k4.y; fk[r][2]=k4.z; fk[r][3]=k4.w;
            fv[r] = tilde_v[(((size_t)b*RR + r)*HH + h)*64 + lane];
        }
    };
    auto load_bnd = [&](int w) {
        const float* p = bnd + w*BNDF;
        #pragma unroll
        for (int j = 0; j < 4; ++j) fs[j] = p[j*64 + lane];
        #pragma unroll
        for (int r = 0; r < 8; ++r) {
            #pragma unroll
            for (int j = 0; j < 4; ++j) fk[r][j] = p[(4 + r*4 + j)*64 + lane];
            fv[r] = p[(36 + r)*64 + lane];
        }
    };
    auto store_bnd = [&](int w) {
        float* p = bnd + w*BNDF;
        #pragma unroll
        for (int j = 0; j < 4; ++j) p[j*64 + lane] = fs[j];
        #pragma unroll
        for (int r = 0; r < 8; ++r) {
            #pragma unroll
            for (int j = 0; j < 4; ++j) p[(4 + r*4 + j)*64 + lane] = fk[r][j];
            p[(36 + r)*64 + lane] = fv[r];
        }
    };
    auto combine = [&](int w) {   // fold true init (bnd[w]) into local state
        const float* p = bnd + w*BNDF;
        #pragma unroll
        for (int j = 0; j < 4; ++j) fs[j] = fmaf(Pg[j], p[j*64 + lane], fs[j]);
        #pragma unroll
        for (int r = 0; r < 8; ++r) {
            #pragma unroll
            for (int j = 0; j < 4; ++j)
                fk[r][j] = fmaf(Pg[j], p[(4 + r*4 + j)*64 + lane], fk[r][j]);
            fv[r] = fmaf(Pb, p[(36 + r)*64 + lane], fv[r]);
        }
    };

    struct Raw { float k, q, v, be, ga; float4 P1, P2, P3; };
    auto load_raw = [&](int t, Raw& rw) {
        const float* prow = proj + (size_t)(t*BBATCH + b) * NPROJ;
        const float* p5 = prow + h*320;
        rw.k  = p5[lane];
        rw.q  = p5[64  + lane];
        rw.v  = p5[128 + lane];
        rw.be = p5[192 + lane];
        rw.ga = p5[256 + lane];
        const float* pp = prow + KQV + h*12;      // wave-uniform -> s_load
        rw.P1 = *(const float4*)(pp);
        rw.P2 = *(const float4*)(pp + 4);
        rw.P3 = *(const float4*)(pp + 8);
    };

    auto sweep = [&](bool out) {
        Pg[0]=Pg[1]=Pg[2]=Pg[3]=1.f; Pb=1.f;
        Raw cur, nxt;
        load_raw(t0, cur);
        for (int i = 0; i < CHK; ++i) {
            const int t = t0 + i;
            if (i + 1 < CHK) load_raw(t + 1, nxt);
            const int tm = __builtin_amdgcn_readlane(tmv, i);
            const float mask = 1.0f - (float)tm;
            float kr = fmaxf(cur.k, 0.f);
            float sg = sigmoidf_(cur.ga);
            float sb = sigmoidf_(cur.be);
            float vg = cur.v * sb;
            float db = (1.f - sb) * mask;
            float p1a[4] = {cur.P1.x, cur.P1.y, cur.P1.z, cur.P1.w};
            float p3a[4] = {cur.P3.x, cur.P3.y, cur.P3.z, cur.P3.w};
            float kg[4], dg[4];
            #pragma unroll
            for (int j = 0; j < 4; ++j) {
                float gexp = sg * sigmoidf_(p3a[j]);
                kg[j] = kr * fmaxf(p1a[j], 0.f) * gexp;
                dg[j] = (1.f - gexp) * mask;
            }
            float occ[8];
            {
                float4 o0 = *(const float4*)(occt + t*8);
                float4 o1 = *(const float4*)(occt + t*8 + 4);
                occ[0]=o0.x; occ[1]=o0.y; occ[2]=o0.z; occ[3]=o0.w;
                occ[4]=o1.x; occ[5]=o1.y; occ[6]=o1.z; occ[7]=o1.w;
            }
            #pragma unroll
            for (int j = 0; j < 4; ++j) {
                fs[j] = fmaf(dg[j], fs[j], kg[j]);
                Pg[j] *= dg[j];
            }
            #pragma unroll
            for (int r = 0; r < 8; ++r) {
                #pragma unroll
                for (int j = 0; j < 4; ++j)
                    fk[r][j] = fmaf(dg[j], fk[r][j], kg[j]*occ[r]);
                fv[r] = fmaf(db, fv[r], vg*occ[r]);
            }
            Pb *= db;
            if (out) {
                float qr = fmaxf(cur.q, 0.f);
                float p2a[4] = {cur.P2.x, cur.P2.y, cur.P2.z, cur.P2.w};
                float qe[4];
                #pragma unroll
                for (int j = 0; j < 4; ++j) qe[j] = qr * fmaxf(p2a[j], 0.f);
                float snorm = fs[0]*qe[0] + fs[1]*qe[1] + fs[2]*qe[2] + fs[3]*qe[3];
                float nrm_u = wave_sum_u(snorm);
                float kdq_u[8];
                #pragma unroll
                for (int r = 0; r < 8; ++r) {
                    float kdq = fk[r][0]*qe[0] + fk[r][1]*qe[1]
                              + fk[r][2]*qe[2] + fk[r][3]*qe[3];
                    kdq_u[r] = wave_sum_u(kdq);
                }
                float kv = 0.f;
                #pragma unroll
                for (int r = 0; r < 8; ++r) kv = fmaf(fv[r], kdq_u[r], kv);
                attn[(size_t)(t*BBATCH + b)*DM + h*64 + lane] =
                    __float2bfloat16(kv / (16.f * (nrm_u + 1e-6f)));
            }
            cur = nxt;
        }
    };

    // ---- pass 1: parallel local scans (chunk 3 skips: it never posts) ----
    if (wv < NCH - 1) {
        if (wv == 0) load_init(); else zero_state();
        sweep(false);
        if (wv > 0) {
            while (__hip_atomic_load(&flags[wv-1], __ATOMIC_ACQUIRE,
                                     __HIP_MEMORY_SCOPE_WORKGROUP) == 0)
                __builtin_amdgcn_s_sleep(1);
            combine(wv - 1);
        }
        store_bnd(wv);
        if (lane == 0)
            __hip_atomic_store(&flags[wv], 1, __ATOMIC_RELEASE,
                               __HIP_MEMORY_SCOPE_WORKGROUP);
    }

    // ---- pass 2: replay from exact chunk-start state, with outputs ------
    if (wv == 0) {
        load_init();
    } else {
        while (__hip_atomic_load(&flags[wv-1], __ATOMIC_ACQUIRE,
                                 __HIP_MEMORY_SCOPE_WORKGROUP) == 0)
            __builtin_amdgcn_s_sleep(1);
        load_bnd(wv - 1);
    }
    sweep(true);
}

// GRU1 final fused with LN2 (A1h 512-stride)
__global__ __launch_bounds__(256) void gru_final_ln(
    const float* __restrict__ A1h, const float* __restrict__ C2,
    const float* __restrict__ z, const float* __restrict__ x,
    const float* __restrict__ g, const float* __restrict__ bta,
    float* __restrict__ g1, __hip_bfloat16* __restrict__ g1b,
    __hip_bfloat16* __restrict__ fib)
{
    int row = blockIdx.x;
    int tid = threadIdx.x;
    size_t base = (size_t)row * DM;
    float2 c2v = ((const float2*)(C2 + base))[tid];
    float2 zv  = ((const float2*)(z  + base))[tid];
    float2 xv  = ((const float2*)(x  + base))[tid];
    float2 av  = ((const float2*)(A1h + base))[tid];
    float h0 = tanhf(av.x + c2v.x);
    float h1 = tanhf(av.y + c2v.y);
    float2 v;
    v.x = (1.0f - zv.x) * xv.x + zv.x * h0;
    v.y = (1.0f - zv.y) * xv.y + zv.y * h1;
    ((float2*)(g1 + base))[tid] = v;
    g1b[base + 2*tid+0] = __float2bfloat16(v.x);
    g1b[base + 2*tid+1] = __float2bfloat16(v.y);

    float s = v.x + v.y;
    #pragma unroll
    for (int off = 32; off; off >>= 1) s += __shfl_down(s, off);
    __shared__ float red[8];
    int wid = tid >> 6, lane = tid & 63;
    if (lane == 0) red[wid] = s;
    __syncthreads();
    if (tid == 0) red[0] = (red[0] + red[1] + red[2] + red[3]) * (1.0f / DM);
    __syncthreads();
    float mean = red[0];
    float dx = v.x - mean, dy = v.y - mean;
    float sq = dx*dx + dy*dy;
    #pragma unroll
    for (int off = 32; off; off >>= 1) sq += __shfl_down(sq, off);
    if (lane == 0) red[4 + wid] = sq;
    __syncthreads();
    if (tid == 0) red[1] = rsqrtf((red[4]+red[5]+red[6]+red[7]) * (1.0f/DM) + 1e-5f);
    __syncthreads();
    float rstd = red[1];
    float2 gg = ((const float2*)g)[tid];
    float2 bb = ((const float2*)bta)[tid];
    fib[base + 2*tid+0] = __float2bfloat16(dx * rstd * gg.x + bb.x);
    fib[base + 2*tid+1] = __float2bfloat16(dy * rstd * gg.y + bb.y);
}

// ---------------- launch --------------------------------------------------
extern "C" void kernel_launch(void* const* d_in, const int* in_sizes, int n_in,
                              void* d_out, int out_size, void* d_ws, size_t ws_size,
                              hipStream_t stream)
{
    const float* inputs = (const float*)d_in[0];
    const int*   term   = (const int*)  d_in[1];
    const float* tilde_k= (const float*)d_in[2];
    const float* tilde_v= (const float*)d_in[3];
    const float* s_prev = (const float*)d_in[4];
    const float* tick   = (const float*)d_in[5];
    const float* w_proj = (const float*)d_in[6];
    const float* b_proj = (const float*)d_in[7];
    const float* w_attn = (const float*)d_in[8];
    const float* b_attn = (const float*)d_in[9];
    const float* ln1_g  = (const float*)d_in[10];
    const float* ln1_b  = (const float*)d_in[11];
    const float* ln2_g  = (const float*)d_in[12];
    const float* ln2_b  = (const float*)d_in[13];
    const float* gru1_w = (const float*)d_in[14];
    const float* gru1_u = (const float*)d_in[15];
    const float* gru2_w = (const float*)d_in[16];
    const float* gru2_u = (const float*)d_in[17];
    const float* ffc_w1 = (const float*)d_in[18];
    const float* ffc_b1 = (const float*)d_in[19];
    const float* ffc_w2 = (const float*)d_in[20];
    const float* ffc_b2 = (const float*)d_in[21];
    float* out = (float*)d_out;
    float* ws  = (float*)d_ws;

    // ---- f32 region (floats) ----
    float* proj = ws;                       // 4096x2656 (dead after scan)
    float* A1h  = ws;                       // 4096x512  (overlays proj)
    float* C2   = ws + 10878976;            // 4096x512
    float* zb   = ws + 12976128;            // 4096x512
    float* g1   = ws + 15073280;            // 4096x512
    // ---- bf16 region ----
    __hip_bfloat16* bb = (__hip_bfloat16*)(ws + 17170432);
    __hip_bfloat16* wp_bf  = bb + 0;          // 2656x512
    __hip_bfloat16* wat_bf = bb + 1359872;    // 512x512
    __hip_bfloat16* g1w_bf = bb + 1622016;    // 3x512x512
    __hip_bfloat16* g1u_bf = bb + 2408448;
    __hip_bfloat16* g2w_bf = bb + 3194880;
    __hip_bfloat16* g2u_bf = bb + 3981312;
    __hip_bfloat16* fw1_bf = bb + 4767744;    // 2048x512
    __hip_bfloat16* fw2_bf = bb + 5816320;    // 512x2048
    __hip_bfloat16* in_bf  = bb + 6864896;    // 4096x512
    __hip_bfloat16* xn_bf  = bb + 8962048;
    __hip_bfloat16* at_bf  = bb + 11059200;
    __hip_bfloat16* y1_bf  = bb + 13156352;
    __hip_bfloat16* rx_bf  = bb + 15253504;
    __hip_bfloat16* fi_bf  = bb + 17350656;
    __hip_bfloat16* mid_bf = bb + 19447808;   // 4096x2048
    __hip_bfloat16* fo_bf  = bb + 27836416;
    __hip_bfloat16* g1_bf  = bb + 29933568;
    // Bx after bf16 region — never overlaps proj.
    float* Bx = ws + 33185792;   // 4096x1024

    dim3 blk(256);

    // 1. merged f32->bf16 conversions + LN1 (one launch)
    F2B9 fa;
    const float* srcs[9] = {w_proj, w_attn, gru1_w, gru1_u, gru2_w, gru2_u,
                            ffc_w1, ffc_w2, inputs};
    __hip_bfloat16* dsts[9] = {wp_bf, wat_bf, g1w_bf, g1u_bf, g2w_bf, g2u_bf,
                               fw1_bf, fw2_bf, in_bf};
    int quads[9] = {339968, 65536, 196608, 196608, 196608, 196608,
                    262144, 262144, 524288};
    int cum = 0;
    for (int i = 0; i < 9; ++i) { fa.s[i] = srcs[i]; fa.d[i] = dsts[i]; fa.cum[i] = cum; cum += quads[i]; }
    fa.cum[9] = cum;
    f2b_ln_all<<<8752 + MM, blk, 0, stream>>>(fa, inputs, ln1_g, ln1_b, xn_bf);

    // 2. projection
    gemm_bf16<<<dim3(21, 32), blk, 0, stream>>>(xn_bf, wp_bf, b_proj, proj, nullptr, NPROJ, DM, 0);

    // 3. chunk-parallel scans + attention + GRU1's Bx GEMM
    size_t dyn = (size_t)(3*BNDF + TT*8 + 4) * 4;   // ~37.9 KB (>= gemm's 16 KB)
    scan_attn_fused<<<512, blk, dyn, stream>>>(proj, term, tick, tilde_k, tilde_v,
                                               s_prev, at_bf, in_bf, g1u_bf, Bx);

    // 4. attn out-proj (+relu) — 64x64 tiles
    gemm_bf16_s<<<dim3(8, 64), blk, 0, stream>>>(at_bf, wat_bf, b_attn, nullptr, y1_bf, DM, DM, 1);

    // 5. GRU1: A-GEMM (64x128, fused r/z); C-GEMM; final+LN2
    gemm_gruA_64<<<dim3(12, 64), blk, 0, stream>>>(y1_bf, g1w_bf, Bx, inputs, rx_bf, zb, A1h);
    gemm_bf16_s<<<dim3(8, 64), blk, 0, stream>>>(rx_bf, g1u_bf + 2*DM*DM, nullptr, C2, nullptr, DM, DM, 0);
    gru_final_ln<<<MM, blk, 0, stream>>>(A1h, C2, zb, inputs, ln2_g, ln2_b, g1, g1_bf, fi_bf);

    // 6. FFC1 + GRU2's Bx GEMM (one launch)
    ffc1_bx_dual<<<dim3(24, 32), blk, 0, stream>>>(fi_bf, fw1_bf, ffc_b1, mid_bf,
                                                   2048, 16,
                                                   g1_bf, g2u_bf, Bx, 1024, DM);

    // 7. FFC2 (+relu) — 64x64 tiles
    gemm_bf16_s<<<dim3(8, 64), blk, 0, stream>>>(mid_bf, fw2_bf, ffc_b2, nullptr, fo_bf, DM, 2048, 1);

    // 8. GRU2: A-GEMM (64x128, fused r/z); C-GEMM (fused final, writes out)
    gemm_gruA_64<<<dim3(12, 64), blk, 0, stream>>>(fo_bf, g2w_bf, Bx, g1, rx_bf, zb, A1h);
    gemm_gruC2_s<<<dim3(8, 64), blk, 0, stream>>>(rx_bf, g2u_bf + 2*DM*DM, A1h, zb, g1, out);
}